// Round 10
// baseline (306.208 us; speedup 1.0000x reference)
//
#include <hip/hip_runtime.h>
#include <hip/hip_bf16.h>

#define NEG_SLOPE 0.01f
#define BNODES 256      // nodes per bucket (dst>>8)
#define NBE 256         // blocks for hist/scatter edge passes

typedef __attribute__((ext_vector_type(8))) short short8;
typedef __attribute__((ext_vector_type(4))) float f32x4;
typedef __attribute__((ext_vector_type(2))) float f32x2;

__device__ __forceinline__ unsigned short f2bf(float f) {
  unsigned int u = __float_as_uint(f);
  u = (u + 0x7fffu + ((u >> 16) & 1u)) >> 16;
  return (unsigned short)u;
}

// ---------- fp8 pack/unpack (HW cvt if available; consistent manual fallback) ----------
#if defined(__has_builtin)
#if __has_builtin(__builtin_amdgcn_cvt_pk_f32_fp8) && __has_builtin(__builtin_amdgcn_cvt_pk_fp8_f32)
#define HAS_FP8_CVT 1
#endif
#endif
#ifndef HAS_FP8_CVT
#define HAS_FP8_CVT 0
#endif

__device__ __forceinline__ float dec1(unsigned b) {
  unsigned s = (b & 0x80u) << 24;
  unsigned em = b & 0x7fu;
  float v = (em < 8) ? (float)em * 0.001953125f
          : __uint_as_float((((em >> 3) + 120u) << 23) | ((em & 7u) << 20));
  return __uint_as_float(s ^ __float_as_uint(v));
}

__device__ __forceinline__ unsigned enc1(float f) {
  unsigned u = __float_as_uint(f);
  unsigned s = (u >> 24) & 0x80u;
  float a = fabsf(f);
  a = fminf(a, 480.f);
  unsigned code;
  if (a < 0.015625f) {
    code = (unsigned)__float2int_rn(a * 512.f);
  } else {
    unsigned ua = __float_as_uint(a);
    unsigned r = ua + 0x7ffffu + ((ua >> 20) & 1u);
    code = (((r >> 23) - 120u) << 3) | ((r >> 20) & 7u);
    if (code > 0x7fu) code = 0x7fu;
  }
  return s | code;
}

template<bool HI>
__device__ __forceinline__ f32x2 fp8pair(unsigned int w) {
#if HAS_FP8_CVT
  return __builtin_amdgcn_cvt_pk_f32_fp8((int)w, HI);
#else
  unsigned sh = HI ? 16u : 0u;
  f32x2 r;
  r[0] = dec1((w >> sh) & 0xffu);
  r[1] = dec1((w >> (sh + 8)) & 0xffu);
  return r;
#endif
}

template<bool HI>
__device__ __forceinline__ unsigned fp8pack(float a, float b, unsigned old) {
#if HAS_FP8_CVT
  return (unsigned)__builtin_amdgcn_cvt_pk_fp8_f32(a, b, (int)old, HI);
#else
  unsigned code = enc1(a) | (enc1(b) << 8);
  return HI ? ((old & 0x0000ffffu) | (code << 16)) : ((old & 0xffff0000u) | code);
#endif
}

// bf16x2 words -> fp8x4 words. out word d of a row = cols 4d..4d+3.
__global__ __launch_bounds__(256) void k_tofp8(const unsigned int* __restrict__ in,
    unsigned int* __restrict__ out8, int nwords_out)
{
  int i = blockIdx.x * 256 + threadIdx.x;
  if (i >= nwords_out) return;
  uint2 w = *(const uint2*)(in + (size_t)i * 2);   // 4 bf16
  float f0 = __uint_as_float(w.x << 16);
  float f1 = __uint_as_float(w.x & 0xffff0000u);
  float f2 = __uint_as_float(w.y << 16);
  float f3 = __uint_as_float(w.y & 0xffff0000u);
  unsigned r = 0;
  r = fp8pack<false>(f0, f1, r);
  r = fp8pack<true >(f2, f3, r);
  out8[i] = r;
}

// ---- weight prep: 5x [128,128] f32 row-major -> bf16 transposed [col][k] ----
__global__ __launch_bounds__(256) void k_prep_w(
    const float* __restrict__ w0, const float* __restrict__ w1,
    const float* __restrict__ w2, const float* __restrict__ w3,
    const float* __restrict__ w4, unsigned short* __restrict__ out)
{
  const float* srcs[5] = {w0, w1, w2, w3, w4};
  const float* s = srcs[blockIdx.x];
  unsigned short* o = out + (size_t)blockIdx.x * 16384;
  for (int i = threadIdx.x; i < 16384; i += 256) {
    int c = i >> 7, k = i & 127;
    o[i] = f2bf(s[(size_t)k * 128 + c]);   // Wt[c][k] = W[k][c]
  }
}

// ---- standalone MFMA GEMM (used for the input projection only) ----
template<bool ACT, bool HAS2, bool A1F32>
__global__ __launch_bounds__(256) void k_mgemm(
    const void* __restrict__ A1v, const unsigned short* __restrict__ Wt1,
    const float* __restrict__ bias,
    const unsigned short* __restrict__ A2b, const unsigned short* __restrict__ Wt2,
    unsigned short* __restrict__ Cb, int nrows)
{
  const int t    = threadIdx.x;
  const int wave = t >> 6;
  const int lane = t & 63;
  const int lr   = lane & 15;
  const int lg   = lane >> 4;
  const int r0   = blockIdx.x * 64 + wave * 16;
  int arow = r0 + lr; if (arow >= nrows) arow = nrows - 1;

  f32x4 acc[8];
  #pragma unroll
  for (int i = 0; i < 8; ++i) acc[i] = (f32x4){0.f, 0.f, 0.f, 0.f};

  const int np = HAS2 ? 2 : 1;
  for (int p = 0; p < np; ++p) {
    const unsigned short* __restrict__ Wt = p ? Wt2 : Wt1;
    #pragma unroll
    for (int ks = 0; ks < 4; ++ks) {
      const int k0 = ks * 32 + lg * 8;
      short8 av;
      if (A1F32 && p == 0) {
        const float* A = (const float*)A1v;
        float4 f0 = *(const float4*)(A + (size_t)arow * 128 + k0);
        float4 f1 = *(const float4*)(A + (size_t)arow * 128 + k0 + 4);
        av[0] = (short)f2bf(f0.x); av[1] = (short)f2bf(f0.y);
        av[2] = (short)f2bf(f0.z); av[3] = (short)f2bf(f0.w);
        av[4] = (short)f2bf(f1.x); av[5] = (short)f2bf(f1.y);
        av[6] = (short)f2bf(f1.z); av[7] = (short)f2bf(f1.w);
      } else {
        const unsigned short* Ab = p ? A2b : (const unsigned short*)A1v;
        av = *(const short8*)(Ab + (size_t)arow * 128 + k0);
      }
      #pragma unroll
      for (int cb = 0; cb < 8; ++cb) {
        short8 bv = *(const short8*)(Wt + (size_t)(cb * 16 + lr) * 128 + k0);
        acc[cb] = __builtin_amdgcn_mfma_f32_16x16x32_bf16(av, bv, acc[cb], 0, 0, 0);
      }
    }
  }

  #pragma unroll
  for (int cb = 0; cb < 8; ++cb) {
    const int col = cb * 16 + lr;
    const float bcol = bias[col];
    #pragma unroll
    for (int reg = 0; reg < 4; ++reg) {
      int r = r0 + lg * 4 + reg;
      if (r < nrows) {
        float o = acc[cb][reg] + bcol;
        if (ACT) o = o > 0.f ? o : o * NEG_SLOPE;
        Cb[(size_t)r * 128 + col] = f2bf(o);
      }
    }
  }
}

// ---- FUSED: per block b, aggregate rows [64b,64b+64) from fp8 mirror into
// swizzled LDS, then dual MFMA GEMM: out = aggLDS@Wtl + bias + root@Wtr. ----
__global__ __launch_bounds__(1024) void k_fused(
    const unsigned int* __restrict__ x8, const int* __restrict__ adj,
    const int* __restrict__ offs2, const int* __restrict__ cnt,
    const unsigned short* __restrict__ rootb,
    const unsigned short* __restrict__ Wtl, const unsigned short* __restrict__ Wtr,
    const float* __restrict__ bias,
    unsigned short* __restrict__ outb, int N)
{
  __shared__ char smem[16384];   // 64 rows x 128 bf16, XOR-swizzled
  const int tid  = threadIdx.x;
  const int wave = tid >> 6;
  const int lane = tid & 63;
  const int l    = lane & 15;
  const int q    = lane >> 4;
  const int b    = blockIdx.x;

  // ---- Phase 1: mean aggregation, 4 nodes per wave ----
  for (int i = 0; i < 4; ++i) {
    const int nl   = i * 16 + wave;     // local row 0..63
    const int node = b * 64 + nl;
    f32x2 acc[4];
    #pragma unroll
    for (int j = 0; j < 4; ++j) acc[j] = (f32x2){0.f, 0.f};
    int c = 0;
    if (node < N) {
      c = cnt[node];
      const int* __restrict__ a = adj + offs2[node];
      if (c > 0) {
        const int cm1 = c - 1;
        for (int e0 = 0; e0 < c; e0 += 32) {
          int idx[8];
          #pragma unroll
          for (int s = 0; s < 8; ++s)
            idx[s] = a[min(e0 + s * 4 + q, cm1)];
          uint2 v[8];
          #pragma unroll
          for (int s = 0; s < 8; ++s)
            v[s] = *(const uint2*)(x8 + (size_t)idx[s] * 32 + l * 2);
          #pragma unroll
          for (int s = 0; s < 8; ++s) {
            float m = (e0 + s * 4 + q < c) ? 1.f : 0.f;
            f32x2 mm = (f32x2){m, m};
            acc[0] += mm * fp8pair<false>(v[s].x);
            acc[1] += mm * fp8pair<true >(v[s].x);
            acc[2] += mm * fp8pair<false>(v[s].y);
            acc[3] += mm * fp8pair<true >(v[s].y);
          }
        }
        #pragma unroll
        for (int j = 0; j < 4; ++j) {
          float a0 = acc[j][0], a1 = acc[j][1];
          a0 += __shfl_xor(a0, 16, 64);
          a0 += __shfl_xor(a0, 32, 64);
          a1 += __shfl_xor(a1, 16, 64);
          a1 += __shfl_xor(a1, 32, 64);
          acc[j][0] = a0; acc[j][1] = a1;
        }
      }
    }
    if (q == 0) {                        // 16 lanes: lane l -> cols 8l..8l+7
      float sc = (c > 0) ? 1.f / (float)c : 0.f;
      uint4 w;
      w.x = (unsigned)f2bf(acc[0][0] * sc) | ((unsigned)f2bf(acc[0][1] * sc) << 16);
      w.y = (unsigned)f2bf(acc[1][0] * sc) | ((unsigned)f2bf(acc[1][1] * sc) << 16);
      w.z = (unsigned)f2bf(acc[2][0] * sc) | ((unsigned)f2bf(acc[2][1] * sc) << 16);
      w.w = (unsigned)f2bf(acc[3][0] * sc) | ((unsigned)f2bf(acc[3][1] * sc) << 16);
      unsigned bo_ = (unsigned)((nl * 256 + l * 16) ^ ((nl & 7) << 4));
      *(uint4*)(smem + bo_) = w;
    }
  }
  __syncthreads();

  // ---- Phase 2: dual GEMM; wave = (wr,wc): rows wr*16+, cols wc*32+ ----
  const int wr = wave & 3;
  const int wc = wave >> 2;
  f32x4 acc2[2];
  acc2[0] = (f32x4){0.f, 0.f, 0.f, 0.f};
  acc2[1] = (f32x4){0.f, 0.f, 0.f, 0.f};
  const int rl = wr * 16 + l;            // local A row 0..63
  int arow = b * 64 + rl; if (arow >= N) arow = N - 1;

  #pragma unroll
  for (int ks = 0; ks < 4; ++ks) {       // p=0: A from swizzled LDS
    const int k0 = ks * 32 + q * 8;
    short8 av = *(const short8*)(smem + ((rl * 256 + ks * 64 + q * 16) ^ ((rl & 7) << 4)));
    #pragma unroll
    for (int j = 0; j < 2; ++j) {
      int cb = wc * 2 + j;
      short8 bv = *(const short8*)(Wtl + (size_t)(cb * 16 + l) * 128 + k0);
      acc2[j] = __builtin_amdgcn_mfma_f32_16x16x32_bf16(av, bv, acc2[j], 0, 0, 0);
    }
  }
  #pragma unroll
  for (int ks = 0; ks < 4; ++ks) {       // p=1: A = root rows from global
    const int k0 = ks * 32 + q * 8;
    short8 av = *(const short8*)(rootb + (size_t)arow * 128 + k0);
    #pragma unroll
    for (int j = 0; j < 2; ++j) {
      int cb = wc * 2 + j;
      short8 bv = *(const short8*)(Wtr + (size_t)(cb * 16 + l) * 128 + k0);
      acc2[j] = __builtin_amdgcn_mfma_f32_16x16x32_bf16(av, bv, acc2[j], 0, 0, 0);
    }
  }

  #pragma unroll
  for (int j = 0; j < 2; ++j) {
    const int col = (wc * 2 + j) * 16 + l;
    const float bc = bias[col];
    #pragma unroll
    for (int reg = 0; reg < 4; ++reg) {
      int r = b * 64 + wr * 16 + q * 4 + reg;   // C/D: row=(lane>>4)*4+reg
      if (r < N) outb[(size_t)r * 128 + col] = f2bf(acc2[j][reg] + bc);
    }
  }
}

// --- bucketize: counting sort of edges by dst>>8 (transposed hist/offs layout) ---

__global__ __launch_bounds__(256) void k_hist(const int* __restrict__ dst,
    int* __restrict__ hist, int E, int NB)
{
  __shared__ int lh[256];
  int t = threadIdx.x;
  lh[t] = 0;
  __syncthreads();
  int chunk = (E + NBE - 1) / NBE;
  int s = blockIdx.x * chunk;
  int e = min(E, s + chunk);
  for (int i = s + t; i < e; i += 256)
    atomicAdd(&lh[dst[i] >> 8], 1);
  __syncthreads();
  hist[blockIdx.x * 256 + t] = lh[t];
  (void)NB;
}

__global__ __launch_bounds__(256) void k_scan(const int* __restrict__ hist,
    int* __restrict__ offs, int NB)
{
  __shared__ int tot[256];
  int t = threadIdx.x;
  int run = 0;
  for (int b = 0; b < NBE; ++b) run += hist[b * 256 + t];
  tot[t] = run;
  __syncthreads();
  int val = run;
  for (int o = 1; o < 256; o <<= 1) {
    int x = (t >= o) ? tot[t - o] : 0;
    __syncthreads();
    val += x; tot[t] = val;
    __syncthreads();
  }
  int acc = val - run;
  for (int b = 0; b < NBE; ++b) {
    offs[b * 256 + t] = acc;
    acc += hist[b * 256 + t];
  }
  (void)NB;
}

// rec = (dst&255)<<16 | src  (src < 65536)
__global__ __launch_bounds__(256) void k_scatter(const int* __restrict__ src,
    const int* __restrict__ dst, const int* __restrict__ offs,
    unsigned int* __restrict__ recs, int E, int NB)
{
  __shared__ int lcnt[256];
  __shared__ int loff[256];
  int t = threadIdx.x;
  lcnt[t] = 0;
  loff[t] = offs[blockIdx.x * 256 + t];
  __syncthreads();
  int chunk = (E + NBE - 1) / NBE;
  int s = blockIdx.x * chunk;
  int e = min(E, s + chunk);
  for (int i = s + t; i < e; i += 256) {
    int d = dst[i];
    int b = d >> 8;
    int r = atomicAdd(&lcnt[b], 1);
    recs[loff[b] + r] = ((unsigned int)(d & 255) << 16) | (unsigned int)src[i];
  }
  (void)NB;
}

// --- within-bucket counting sort -> per-node CSR (int LDS atomics only) ---
__global__ __launch_bounds__(256) void k_csr(const unsigned int* __restrict__ recs,
    const int* __restrict__ offs, int* __restrict__ adj,
    int* __restrict__ offs2, int* __restrict__ cnt, int N, int NB, int E)
{
  __shared__ int lcnt[256];
  __shared__ int lpos[256];
  const int t  = threadIdx.x;
  const int b  = blockIdx.x;
  const int bs = offs[b];
  const int be = (b + 1 < NB) ? offs[b + 1] : E;
  lcnt[t] = 0;
  __syncthreads();
  for (int i = bs + t; i < be; i += 256)
    atomicAdd(&lcnt[recs[i] >> 16], 1);
  __syncthreads();
  int v = lcnt[t];
  lpos[t] = v;
  __syncthreads();
  int val = v;
  for (int o = 1; o < 256; o <<= 1) {
    int x = (t >= o) ? lpos[t - o] : 0;
    __syncthreads();
    val += x; lpos[t] = val;
    __syncthreads();
  }
  int excl = val - v;
  int node = b * BNODES + t;
  if (node < N) { cnt[node] = v; offs2[node] = bs + excl; }
  lcnt[t] = excl;
  __syncthreads();
  for (int i = bs + t; i < be; i += 256) {
    unsigned int r = recs[i];
    int ld = r >> 16;
    int p = atomicAdd(&lcnt[ld], 1);
    adj[bs + p] = (int)(r & 0xffffu);
  }
}

// out[r][0..2] = x2[r] @ W_out + b_out; x2 is bf16-packed words.
__global__ __launch_bounds__(256) void k_out(const unsigned int* __restrict__ x2w,
    const float* __restrict__ Wo, const float* __restrict__ bo,
    float* __restrict__ out, int n)
{
  int wid  = (blockIdx.x * 256 + threadIdx.x) >> 6;
  int nw   = (gridDim.x * 256) >> 6;
  int lane = threadIdx.x & 63;
  float w0a = Wo[(2*lane)*3 + 0], w0b = Wo[(2*lane)*3 + 1], w0c = Wo[(2*lane)*3 + 2];
  float w1a = Wo[(2*lane+1)*3 + 0], w1b = Wo[(2*lane+1)*3 + 1], w1c = Wo[(2*lane+1)*3 + 2];
  float b0 = bo[0], b1 = bo[1], b2 = bo[2];
  for (int r = wid; r < n; r += nw) {
    unsigned int v = x2w[(size_t)r * 64 + lane];
    float xl = __uint_as_float(v << 16);
    float xh = __uint_as_float(v & 0xffff0000u);
    float o0 = xl * w0a + xh * w1a;
    float o1 = xl * w0b + xh * w1b;
    float o2 = xl * w0c + xh * w1c;
    for (int off = 32; off; off >>= 1) {
      o0 += __shfl_xor(o0, off, 64);
      o1 += __shfl_xor(o1, off, 64);
      o2 += __shfl_xor(o2, off, 64);
    }
    if (lane == 0) {
      out[(size_t)r * 3 + 0] = o0 + b0;
      out[(size_t)r * 3 + 1] = o1 + b1;
      out[(size_t)r * 3 + 2] = o2 + b2;
    }
  }
}

extern "C" void kernel_launch(void* const* d_in, const int* in_sizes, int n_in,
                              void* d_out, int out_size, void* d_ws, size_t ws_size,
                              hipStream_t stream)
{
  const float* feature = (const float*)d_in[0];
  const int*   ei      = (const int*)d_in[1];
  // d_in[2] edge_type: unused by the reference
  const float* W_in = (const float*)d_in[3];
  const float* b_in = (const float*)d_in[4];
  const float* W1l  = (const float*)d_in[5];
  const float* b1l  = (const float*)d_in[6];
  const float* W1r  = (const float*)d_in[7];
  const float* W2l  = (const float*)d_in[8];
  const float* b2l  = (const float*)d_in[9];
  const float* W2r  = (const float*)d_in[10];
  const float* Wo   = (const float*)d_in[11];
  const float* bo   = (const float*)d_in[12];
  float* out = (float*)d_out;

  const int N = in_sizes[0] / 128;
  const int E = in_sizes[1] / 2;
  const int NB = (N + BNODES - 1) / BNODES;
  const int* src = ei;
  const int* dst = ei + E;

  char* ws = (char*)d_ws;
  size_t off = 0;
  auto alloc = [&](size_t bytes) {
    char* p = ws + off;
    off = (off + bytes + 255) & ~(size_t)255;
    return p;
  };
  unsigned int* xb    = (unsigned int*)alloc((size_t)N * 64 * 4); // bf16 x0
  unsigned int* yb    = (unsigned int*)alloc((size_t)N * 64 * 4); // bf16 x1
  unsigned int* zb    = (unsigned int*)alloc((size_t)N * 64 * 4); // bf16 x2
  unsigned int* x8    = (unsigned int*)alloc((size_t)N * 32 * 4); // fp8 x0
  unsigned int* y8    = (unsigned int*)alloc((size_t)N * 32 * 4); // fp8 x1
  unsigned int* recs  = (unsigned int*)alloc((size_t)E * 4);
  int*          adj   = (int*)alloc((size_t)E * 4);
  int*          hist  = (int*)alloc((size_t)256 * NBE * 4);
  int*          offs  = (int*)alloc((size_t)256 * NBE * 4);
  int*          offs2 = (int*)alloc((size_t)N * 4);
  int*          cnt   = (int*)alloc((size_t)N * 4);
  unsigned short* wtb = (unsigned short*)alloc((size_t)5 * 16384 * 2);
  (void)ws_size; (void)n_in; (void)out_size;

  unsigned short* WtIn = wtb;
  unsigned short* Wt1l = wtb + 16384;
  unsigned short* Wt1r = wtb + 2 * 16384;
  unsigned short* Wt2l = wtb + 3 * 16384;
  unsigned short* Wt2r = wtb + 4 * 16384;

  unsigned short* xbs = (unsigned short*)xb;
  unsigned short* ybs = (unsigned short*)yb;
  unsigned short* zbs = (unsigned short*)zb;

  dim3 blk(256);
  int gGemm = (N + 63) / 64;       // also the fused grid (64 rows/block)
  int gCvt  = (N * 32 + 255) / 256;

  // weight prep + edge bucketing (independent)
  k_prep_w<<<5, blk, 0, stream>>>(W_in, W1l, W1r, W2l, W2r, wtb);
  k_hist<<<NBE, blk, 0, stream>>>(dst, hist, E, NB);
  k_scan<<<1, blk, 0, stream>>>(hist, offs, NB);
  k_scatter<<<NBE, blk, 0, stream>>>(src, dst, offs, recs, E, NB);
  k_csr<<<NB, blk, 0, stream>>>(recs, offs, adj, offs2, cnt, N, NB, E);

  // x0 = leaky_relu(feature @ W_in + b_in)  -> bf16 xb, fp8 x8
  k_mgemm<true,  false, true ><<<gGemm, blk, 0, stream>>>(
      feature, WtIn, b_in, nullptr, nullptr, xbs, N);
  k_tofp8<<<gCvt, blk, 0, stream>>>(xb, x8, N * 32);

  // layer 1 (fused agg+GEMM), then fp8 mirror of y
  k_fused<<<gGemm, dim3(1024), 0, stream>>>(
      x8, adj, offs2, cnt, xbs, Wt1l, Wt1r, b1l, ybs, N);
  k_tofp8<<<gCvt, blk, 0, stream>>>(yb, y8, N * 32);

  // layer 2 (fused agg+GEMM)
  k_fused<<<gGemm, dim3(1024), 0, stream>>>(
      y8, adj, offs2, cnt, ybs, Wt2l, Wt2r, b2l, zbs, N);

  // output projection
  k_out<<<512, blk, 0, stream>>>(zb, Wo, bo, out, N);
}

// Round 11
// 268.800 us; speedup vs baseline: 1.1392x; 1.1392x over previous
//
#include <hip/hip_runtime.h>
#include <hip/hip_bf16.h>

#define NEG_SLOPE 0.01f
#define BNODES 256      // nodes per bucket (dst>>8)
#define NBE 256         // blocks for hist/scatter edge passes

typedef __attribute__((ext_vector_type(8))) short short8;
typedef __attribute__((ext_vector_type(4))) float f32x4;
typedef __attribute__((ext_vector_type(2))) float f32x2;

__device__ __forceinline__ unsigned short f2bf(float f) {
  unsigned int u = __float_as_uint(f);
  u = (u + 0x7fffu + ((u >> 16) & 1u)) >> 16;
  return (unsigned short)u;
}

// ---------- fp8 pack/unpack (HW cvt if available; consistent manual fallback) ----------
#if defined(__has_builtin)
#if __has_builtin(__builtin_amdgcn_cvt_pk_f32_fp8) && __has_builtin(__builtin_amdgcn_cvt_pk_fp8_f32)
#define HAS_FP8_CVT 1
#endif
#endif
#ifndef HAS_FP8_CVT
#define HAS_FP8_CVT 0
#endif

__device__ __forceinline__ float dec1(unsigned b) {
  unsigned s = (b & 0x80u) << 24;
  unsigned em = b & 0x7fu;
  float v = (em < 8) ? (float)em * 0.001953125f
          : __uint_as_float((((em >> 3) + 120u) << 23) | ((em & 7u) << 20));
  return __uint_as_float(s ^ __float_as_uint(v));
}

__device__ __forceinline__ unsigned enc1(float f) {
  unsigned u = __float_as_uint(f);
  unsigned s = (u >> 24) & 0x80u;
  float a = fabsf(f);
  a = fminf(a, 480.f);
  unsigned code;
  if (a < 0.015625f) {
    code = (unsigned)__float2int_rn(a * 512.f);
  } else {
    unsigned ua = __float_as_uint(a);
    unsigned r = ua + 0x7ffffu + ((ua >> 20) & 1u);
    code = (((r >> 23) - 120u) << 3) | ((r >> 20) & 7u);
    if (code > 0x7fu) code = 0x7fu;
  }
  return s | code;
}

template<bool HI>
__device__ __forceinline__ f32x2 fp8pair(unsigned int w) {
#if HAS_FP8_CVT
  return __builtin_amdgcn_cvt_pk_f32_fp8((int)w, HI);
#else
  unsigned sh = HI ? 16u : 0u;
  f32x2 r;
  r[0] = dec1((w >> sh) & 0xffu);
  r[1] = dec1((w >> (sh + 8)) & 0xffu);
  return r;
#endif
}

template<bool HI>
__device__ __forceinline__ unsigned fp8pack(float a, float b, unsigned old) {
#if HAS_FP8_CVT
  return (unsigned)__builtin_amdgcn_cvt_pk_fp8_f32(a, b, (int)old, HI);
#else
  unsigned code = enc1(a) | (enc1(b) << 8);
  return HI ? ((old & 0x0000ffffu) | (code << 16)) : ((old & 0xffff0000u) | code);
#endif
}

// bf16x2 words -> fp8x4 words. out word d of a row = cols 4d..4d+3.
__global__ __launch_bounds__(256) void k_tofp8(const unsigned int* __restrict__ in,
    unsigned int* __restrict__ out8, int nwords_out)
{
  int i = blockIdx.x * 256 + threadIdx.x;
  if (i >= nwords_out) return;
  uint2 w = *(const uint2*)(in + (size_t)i * 2);   // 4 bf16
  float f0 = __uint_as_float(w.x << 16);
  float f1 = __uint_as_float(w.x & 0xffff0000u);
  float f2 = __uint_as_float(w.y << 16);
  float f3 = __uint_as_float(w.y & 0xffff0000u);
  unsigned r = 0;
  r = fp8pack<false>(f0, f1, r);
  r = fp8pack<true >(f2, f3, r);
  out8[i] = r;
}

// ---- weight prep: 5x [128,128] f32 row-major -> bf16 transposed [col][k] ----
__global__ __launch_bounds__(256) void k_prep_w(
    const float* __restrict__ w0, const float* __restrict__ w1,
    const float* __restrict__ w2, const float* __restrict__ w3,
    const float* __restrict__ w4, unsigned short* __restrict__ out)
{
  const float* srcs[5] = {w0, w1, w2, w3, w4};
  const float* s = srcs[blockIdx.x];
  unsigned short* o = out + (size_t)blockIdx.x * 16384;
  for (int i = threadIdx.x; i < 16384; i += 256) {
    int c = i >> 7, k = i & 127;
    o[i] = f2bf(s[(size_t)k * 128 + c]);   // Wt[c][k] = W[k][c]
  }
}

// ---- MFMA GEMM with A-prefetch: Cb = act(A1@W1 + bias (+ A2@W2)) ----
template<bool ACT, bool HAS2, bool A1F32>
__global__ __launch_bounds__(256) void k_mgemm(
    const void* __restrict__ A1v, const unsigned short* __restrict__ Wt1,
    const float* __restrict__ bias,
    const unsigned short* __restrict__ A2b, const unsigned short* __restrict__ Wt2,
    unsigned short* __restrict__ Cb, int nrows)
{
  const int t    = threadIdx.x;
  const int wave = t >> 6;
  const int lane = t & 63;
  const int lr   = lane & 15;
  const int lg   = lane >> 4;
  const int r0   = blockIdx.x * 64 + wave * 16;
  int arow = r0 + lr; if (arow >= nrows) arow = nrows - 1;

  // prefetch ALL A fragments first (8x16B in flight -> hide HBM/L2 latency)
  short8 a1[4], a2[4];
  #pragma unroll
  for (int ks = 0; ks < 4; ++ks) {
    const int k0 = ks * 32 + lg * 8;
    if (A1F32) {
      const float* A = (const float*)A1v;
      float4 f0 = *(const float4*)(A + (size_t)arow * 128 + k0);
      float4 f1 = *(const float4*)(A + (size_t)arow * 128 + k0 + 4);
      a1[ks][0] = (short)f2bf(f0.x); a1[ks][1] = (short)f2bf(f0.y);
      a1[ks][2] = (short)f2bf(f0.z); a1[ks][3] = (short)f2bf(f0.w);
      a1[ks][4] = (short)f2bf(f1.x); a1[ks][5] = (short)f2bf(f1.y);
      a1[ks][6] = (short)f2bf(f1.z); a1[ks][7] = (short)f2bf(f1.w);
    } else {
      a1[ks] = *(const short8*)((const unsigned short*)A1v + (size_t)arow * 128 + k0);
    }
  }
  if (HAS2) {
    #pragma unroll
    for (int ks = 0; ks < 4; ++ks) {
      const int k0 = ks * 32 + lg * 8;
      a2[ks] = *(const short8*)(A2b + (size_t)arow * 128 + k0);
    }
  }

  f32x4 acc[8];
  #pragma unroll
  for (int i = 0; i < 8; ++i) acc[i] = (f32x4){0.f, 0.f, 0.f, 0.f};

  #pragma unroll
  for (int ks = 0; ks < 4; ++ks) {
    const int k0 = ks * 32 + lg * 8;
    #pragma unroll
    for (int cb = 0; cb < 8; ++cb) {
      short8 bv = *(const short8*)(Wt1 + (size_t)(cb * 16 + lr) * 128 + k0);
      acc[cb] = __builtin_amdgcn_mfma_f32_16x16x32_bf16(a1[ks], bv, acc[cb], 0, 0, 0);
    }
  }
  if (HAS2) {
    #pragma unroll
    for (int ks = 0; ks < 4; ++ks) {
      const int k0 = ks * 32 + lg * 8;
      #pragma unroll
      for (int cb = 0; cb < 8; ++cb) {
        short8 bv = *(const short8*)(Wt2 + (size_t)(cb * 16 + lr) * 128 + k0);
        acc[cb] = __builtin_amdgcn_mfma_f32_16x16x32_bf16(a2[ks], bv, acc[cb], 0, 0, 0);
      }
    }
  }

  #pragma unroll
  for (int cb = 0; cb < 8; ++cb) {
    const int col = cb * 16 + lr;
    const float bcol = bias[col];
    #pragma unroll
    for (int reg = 0; reg < 4; ++reg) {
      int r = r0 + lg * 4 + reg;
      if (r < nrows) {
        float o = acc[cb][reg] + bcol;
        if (ACT) o = o > 0.f ? o : o * NEG_SLOPE;
        Cb[(size_t)r * 128 + col] = f2bf(o);
      }
    }
  }
}

// --- bucketize: counting sort of edges by dst>>8 (transposed hist/offs layout) ---

__global__ __launch_bounds__(256) void k_hist(const int* __restrict__ dst,
    int* __restrict__ hist, int E, int NB)
{
  __shared__ int lh[256];
  int t = threadIdx.x;
  lh[t] = 0;
  __syncthreads();
  int chunk = (E + NBE - 1) / NBE;
  int s = blockIdx.x * chunk;
  int e = min(E, s + chunk);
  for (int i = s + t; i < e; i += 256)
    atomicAdd(&lh[dst[i] >> 8], 1);
  __syncthreads();
  hist[blockIdx.x * 256 + t] = lh[t];
  (void)NB;
}

__global__ __launch_bounds__(256) void k_scan(const int* __restrict__ hist,
    int* __restrict__ offs, int NB)
{
  __shared__ int tot[256];
  int t = threadIdx.x;
  int run = 0;
  #pragma unroll 8
  for (int b = 0; b < NBE; ++b) run += hist[b * 256 + t];
  tot[t] = run;
  __syncthreads();
  int val = run;
  for (int o = 1; o < 256; o <<= 1) {
    int x = (t >= o) ? tot[t - o] : 0;
    __syncthreads();
    val += x; tot[t] = val;
    __syncthreads();
  }
  int acc = val - run;
  #pragma unroll 8
  for (int b = 0; b < NBE; ++b) {
    offs[b * 256 + t] = acc;
    acc += hist[b * 256 + t];
  }
  (void)NB;
}

// rec = (dst&255)<<16 | src  (src < 65536)
__global__ __launch_bounds__(256) void k_scatter(const int* __restrict__ src,
    const int* __restrict__ dst, const int* __restrict__ offs,
    unsigned int* __restrict__ recs, int E, int NB)
{
  __shared__ int lcnt[256];
  __shared__ int loff[256];
  int t = threadIdx.x;
  lcnt[t] = 0;
  loff[t] = offs[blockIdx.x * 256 + t];
  __syncthreads();
  int chunk = (E + NBE - 1) / NBE;
  int s = blockIdx.x * chunk;
  int e = min(E, s + chunk);
  for (int i = s + t; i < e; i += 256) {
    int d = dst[i];
    int b = d >> 8;
    int r = atomicAdd(&lcnt[b], 1);
    recs[loff[b] + r] = ((unsigned int)(d & 255) << 16) | (unsigned int)src[i];
  }
  (void)NB;
}

// --- within-bucket counting sort -> per-node CSR (int LDS atomics only) ---
__global__ __launch_bounds__(256) void k_csr(const unsigned int* __restrict__ recs,
    const int* __restrict__ offs, int* __restrict__ adj,
    int* __restrict__ offs2, int* __restrict__ cnt, int N, int NB, int E)
{
  __shared__ int lcnt[256];
  __shared__ int lpos[256];
  const int t  = threadIdx.x;
  const int b  = blockIdx.x;
  const int bs = offs[b];
  const int be = (b + 1 < NB) ? offs[b + 1] : E;
  lcnt[t] = 0;
  __syncthreads();
  for (int i = bs + t; i < be; i += 256)
    atomicAdd(&lcnt[recs[i] >> 16], 1);
  __syncthreads();
  int v = lcnt[t];
  lpos[t] = v;
  __syncthreads();
  int val = v;
  for (int o = 1; o < 256; o <<= 1) {
    int x = (t >= o) ? lpos[t - o] : 0;
    __syncthreads();
    val += x; lpos[t] = val;
    __syncthreads();
  }
  int excl = val - v;
  int node = b * BNODES + t;
  if (node < N) { cnt[node] = v; offs2[node] = bs + excl; }
  lcnt[t] = excl;
  __syncthreads();
  for (int i = bs + t; i < be; i += 256) {
    unsigned int r = recs[i];
    int ld = r >> 16;
    int p = atomicAdd(&lcnt[ld], 1);
    adj[bs + p] = (int)(r & 0xffffu);
  }
}

// Mean aggregation over fp8 rows, XCD-aligned block mapping:
// agg block with (bid%8)==x covers nodes of mgemm block j (j%8==x), so the
// agb rows it writes stay in the same XCD's L2 that the consumer reads from.
__global__ __launch_bounds__(256) void k_agg(const unsigned int* __restrict__ x8,
    const int* __restrict__ adj, const int* __restrict__ offs2,
    const int* __restrict__ cnt, unsigned int* __restrict__ aggb, int n, int nJ)
{
  const int Q   = (nJ + 7) >> 3;
  const int x   = blockIdx.x & 7;
  const int t2  = blockIdx.x >> 3;
  const int jj  = t2 % Q;
  const int sub = t2 / Q;              // 0..15
  const int j   = x + (jj << 3);
  if (j >= nJ) return;
  int node = j * 64 + sub * 4 + (threadIdx.x >> 6);
  if (node >= n) return;

  const int lane = threadIdx.x & 63;
  const int l = lane & 15;
  const int q = lane >> 4;
  const int c = cnt[node];
  const int* __restrict__ a = adj + offs2[node];

  f32x2 acc[4];
  #pragma unroll
  for (int jv = 0; jv < 4; ++jv) acc[jv] = (f32x2){0.f, 0.f};

  if (c > 0) {
    const int cm1 = c - 1;
    for (int e0 = 0; e0 < c; e0 += 32) {
      int idx[8];
      #pragma unroll
      for (int s = 0; s < 8; ++s)
        idx[s] = a[min(e0 + s * 4 + q, cm1)];
      uint2 v[8];
      #pragma unroll
      for (int s = 0; s < 8; ++s)
        v[s] = *(const uint2*)(x8 + (size_t)idx[s] * 32 + l * 2);
      #pragma unroll
      for (int s = 0; s < 8; ++s) {
        float m = (e0 + s * 4 + q < c) ? 1.f : 0.f;
        f32x2 mm = (f32x2){m, m};
        acc[0] += mm * fp8pair<false>(v[s].x);
        acc[1] += mm * fp8pair<true >(v[s].x);
        acc[2] += mm * fp8pair<false>(v[s].y);
        acc[3] += mm * fp8pair<true >(v[s].y);
      }
    }
    #pragma unroll
    for (int jv = 0; jv < 4; ++jv) {
      float a0 = acc[jv][0], a1 = acc[jv][1];
      a0 += __shfl_xor(a0, 16, 64);
      a0 += __shfl_xor(a0, 32, 64);
      a1 += __shfl_xor(a1, 16, 64);
      a1 += __shfl_xor(a1, 32, 64);
      acc[jv][0] = a0; acc[jv][1] = a1;
    }
  }

  if (q == 0) {
    float sc = (c > 0) ? 1.f / (float)c : 0.f;
    uint4 w;
    w.x = (unsigned)f2bf(acc[0][0] * sc) | ((unsigned)f2bf(acc[0][1] * sc) << 16);
    w.y = (unsigned)f2bf(acc[1][0] * sc) | ((unsigned)f2bf(acc[1][1] * sc) << 16);
    w.z = (unsigned)f2bf(acc[2][0] * sc) | ((unsigned)f2bf(acc[2][1] * sc) << 16);
    w.w = (unsigned)f2bf(acc[3][0] * sc) | ((unsigned)f2bf(acc[3][1] * sc) << 16);
    *(uint4*)(aggb + (size_t)node * 64 + l * 4) = w;
  }
}

// out[r][0..2] = x2[r] @ W_out + b_out; block j handles rows 64j.. (XCD-local zb reads)
__global__ __launch_bounds__(256) void k_out(const unsigned int* __restrict__ x2w,
    const float* __restrict__ Wo, const float* __restrict__ bo,
    float* __restrict__ out, int n)
{
  int wave = threadIdx.x >> 6;
  int lane = threadIdx.x & 63;
  float w0a = Wo[(2*lane)*3 + 0], w0b = Wo[(2*lane)*3 + 1], w0c = Wo[(2*lane)*3 + 2];
  float w1a = Wo[(2*lane+1)*3 + 0], w1b = Wo[(2*lane+1)*3 + 1], w1c = Wo[(2*lane+1)*3 + 2];
  float b0 = bo[0], b1 = bo[1], b2 = bo[2];
  int rbase = blockIdx.x * 64 + wave * 16;
  for (int i = 0; i < 16; ++i) {
    int r = rbase + i;
    if (r >= n) break;
    unsigned int v = x2w[(size_t)r * 64 + lane];
    float xl = __uint_as_float(v << 16);
    float xh = __uint_as_float(v & 0xffff0000u);
    float o0 = xl * w0a + xh * w1a;
    float o1 = xl * w0b + xh * w1b;
    float o2 = xl * w0c + xh * w1c;
    for (int off = 32; off; off >>= 1) {
      o0 += __shfl_xor(o0, off, 64);
      o1 += __shfl_xor(o1, off, 64);
      o2 += __shfl_xor(o2, off, 64);
    }
    if (lane == 0) {
      out[(size_t)r * 3 + 0] = o0 + b0;
      out[(size_t)r * 3 + 1] = o1 + b1;
      out[(size_t)r * 3 + 2] = o2 + b2;
    }
  }
}

extern "C" void kernel_launch(void* const* d_in, const int* in_sizes, int n_in,
                              void* d_out, int out_size, void* d_ws, size_t ws_size,
                              hipStream_t stream)
{
  const float* feature = (const float*)d_in[0];
  const int*   ei      = (const int*)d_in[1];
  // d_in[2] edge_type: unused by the reference
  const float* W_in = (const float*)d_in[3];
  const float* b_in = (const float*)d_in[4];
  const float* W1l  = (const float*)d_in[5];
  const float* b1l  = (const float*)d_in[6];
  const float* W1r  = (const float*)d_in[7];
  const float* W2l  = (const float*)d_in[8];
  const float* b2l  = (const float*)d_in[9];
  const float* W2r  = (const float*)d_in[10];
  const float* Wo   = (const float*)d_in[11];
  const float* bo   = (const float*)d_in[12];
  float* out = (float*)d_out;

  const int N = in_sizes[0] / 128;
  const int E = in_sizes[1] / 2;
  const int NB = (N + BNODES - 1) / BNODES;
  const int* src = ei;
  const int* dst = ei + E;

  char* ws = (char*)d_ws;
  size_t off = 0;
  auto alloc = [&](size_t bytes) {
    char* p = ws + off;
    off = (off + bytes + 255) & ~(size_t)255;
    return p;
  };
  unsigned int* xb    = (unsigned int*)alloc((size_t)N * 64 * 4); // bf16 x0
  unsigned int* yb    = (unsigned int*)alloc((size_t)N * 64 * 4); // bf16 x1
  unsigned int* zb    = (unsigned int*)alloc((size_t)N * 64 * 4); // bf16 x2
  unsigned int* agb   = (unsigned int*)alloc((size_t)N * 64 * 4); // bf16 agg
  unsigned int* x8    = (unsigned int*)alloc((size_t)N * 32 * 4); // fp8 x0
  unsigned int* y8    = (unsigned int*)alloc((size_t)N * 32 * 4); // fp8 x1
  unsigned int* recs  = (unsigned int*)alloc((size_t)E * 4);
  int*          adj   = (int*)alloc((size_t)E * 4);
  int*          hist  = (int*)alloc((size_t)256 * NBE * 4);
  int*          offs  = (int*)alloc((size_t)256 * NBE * 4);
  int*          offs2 = (int*)alloc((size_t)N * 4);
  int*          cnt   = (int*)alloc((size_t)N * 4);
  unsigned short* wtb = (unsigned short*)alloc((size_t)5 * 16384 * 2);
  (void)ws_size; (void)n_in; (void)out_size;

  unsigned short* WtIn = wtb;
  unsigned short* Wt1l = wtb + 16384;
  unsigned short* Wt1r = wtb + 2 * 16384;
  unsigned short* Wt2l = wtb + 3 * 16384;
  unsigned short* Wt2r = wtb + 4 * 16384;

  unsigned short* xbs  = (unsigned short*)xb;
  unsigned short* ybs  = (unsigned short*)yb;
  unsigned short* zbs  = (unsigned short*)zb;
  unsigned short* agbs = (unsigned short*)agb;

  dim3 blk(256);
  int gGemm = (N + 63) / 64;
  int Q     = (gGemm + 7) / 8;
  int gAgg  = 8 * Q * 16;          // XCD-aligned agg grid
  int gCvt  = (N * 32 + 255) / 256;

  // weight prep + edge bucketing (independent)
  k_prep_w<<<5, blk, 0, stream>>>(W_in, W1l, W1r, W2l, W2r, wtb);
  k_hist<<<NBE, blk, 0, stream>>>(dst, hist, E, NB);
  k_scan<<<1, blk, 0, stream>>>(hist, offs, NB);
  k_scatter<<<NBE, blk, 0, stream>>>(src, dst, offs, recs, E, NB);
  k_csr<<<NB, blk, 0, stream>>>(recs, offs, adj, offs2, cnt, N, NB, E);

  // x0 = leaky_relu(feature @ W_in + b_in)  -> bf16 xb, fp8 x8
  k_mgemm<true,  false, true ><<<gGemm, blk, 0, stream>>>(
      feature, WtIn, b_in, nullptr, nullptr, xbs, N);
  k_tofp8<<<gCvt, blk, 0, stream>>>(xb, x8, N * 32);

  // layer 1
  k_agg<<<gAgg, blk, 0, stream>>>(x8, adj, offs2, cnt, agb, N, gGemm);
  k_mgemm<false, true,  false><<<gGemm, blk, 0, stream>>>(
      agbs, Wt1l, b1l, xbs, Wt1r, ybs, N);
  k_tofp8<<<gCvt, blk, 0, stream>>>(yb, y8, N * 32);

  // layer 2
  k_agg<<<gAgg, blk, 0, stream>>>(y8, adj, offs2, cnt, agb, N, gGemm);
  k_mgemm<false, true,  false><<<gGemm, blk, 0, stream>>>(
      agbs, Wt2l, b2l, ybs, Wt2r, zbs, N);

  // output projection (block-aligned rows)
  k_out<<<gGemm, blk, 0, stream>>>(zb, Wo, bo, out, N);
}

// Round 12
// 210.317 us; speedup vs baseline: 1.4559x; 1.2781x over previous
//
#include <hip/hip_runtime.h>
#include <hip/hip_bf16.h>

#define NEG_SLOPE 0.01f
#define BNODES 256      // nodes per bucket (dst>>8)
#define NBE 256         // blocks for hist/scatter edge passes

typedef __attribute__((ext_vector_type(8))) short short8;
typedef __attribute__((ext_vector_type(4))) float f32x4;
typedef __attribute__((ext_vector_type(2))) float f32x2;

__device__ __forceinline__ unsigned short f2bf(float f) {
  unsigned int u = __float_as_uint(f);
  u = (u + 0x7fffu + ((u >> 16) & 1u)) >> 16;
  return (unsigned short)u;
}

// ---------- fp8 pack/unpack (HW cvt if available; consistent manual fallback) ----------
#if defined(__has_builtin)
#if __has_builtin(__builtin_amdgcn_cvt_pk_f32_fp8) && __has_builtin(__builtin_amdgcn_cvt_pk_fp8_f32)
#define HAS_FP8_CVT 1
#endif
#endif
#ifndef HAS_FP8_CVT
#define HAS_FP8_CVT 0
#endif

__device__ __forceinline__ float dec1(unsigned b) {
  unsigned s = (b & 0x80u) << 24;
  unsigned em = b & 0x7fu;
  float v = (em < 8) ? (float)em * 0.001953125f
          : __uint_as_float((((em >> 3) + 120u) << 23) | ((em & 7u) << 20));
  return __uint_as_float(s ^ __float_as_uint(v));
}

__device__ __forceinline__ unsigned enc1(float f) {
  unsigned u = __float_as_uint(f);
  unsigned s = (u >> 24) & 0x80u;
  float a = fabsf(f);
  a = fminf(a, 480.f);
  unsigned code;
  if (a < 0.015625f) {
    code = (unsigned)__float2int_rn(a * 512.f);
  } else {
    unsigned ua = __float_as_uint(a);
    unsigned r = ua + 0x7ffffu + ((ua >> 20) & 1u);
    code = (((r >> 23) - 120u) << 3) | ((r >> 20) & 7u);
    if (code > 0x7fu) code = 0x7fu;
  }
  return s | code;
}

template<bool HI>
__device__ __forceinline__ f32x2 fp8pair(unsigned int w) {
#if HAS_FP8_CVT
  return __builtin_amdgcn_cvt_pk_f32_fp8((int)w, HI);
#else
  unsigned sh = HI ? 16u : 0u;
  f32x2 r;
  r[0] = dec1((w >> sh) & 0xffu);
  r[1] = dec1((w >> (sh + 8)) & 0xffu);
  return r;
#endif
}

template<bool HI>
__device__ __forceinline__ unsigned fp8pack(float a, float b, unsigned old) {
#if HAS_FP8_CVT
  return (unsigned)__builtin_amdgcn_cvt_pk_fp8_f32(a, b, (int)old, HI);
#else
  unsigned code = enc1(a) | (enc1(b) << 8);
  return HI ? ((old & 0x0000ffffu) | (code << 16)) : ((old & 0xffff0000u) | code);
#endif
}

// bf16x2 words -> fp8x4 words. out word d of a row = cols 4d..4d+3.
__global__ __launch_bounds__(256) void k_tofp8(const unsigned int* __restrict__ in,
    unsigned int* __restrict__ out8, int nwords_out)
{
  int i = blockIdx.x * 256 + threadIdx.x;
  if (i >= nwords_out) return;
  uint2 w = *(const uint2*)(in + (size_t)i * 2);   // 4 bf16
  float f0 = __uint_as_float(w.x << 16);
  float f1 = __uint_as_float(w.x & 0xffff0000u);
  float f2 = __uint_as_float(w.y << 16);
  float f3 = __uint_as_float(w.y & 0xffff0000u);
  unsigned r = 0;
  r = fp8pack<false>(f0, f1, r);
  r = fp8pack<true >(f2, f3, r);
  out8[i] = r;
}

// ---- weight prep: 5x [128,128] f32 row-major -> bf16 transposed [col][k] ----
__global__ __launch_bounds__(256) void k_prep_w(
    const float* __restrict__ w0, const float* __restrict__ w1,
    const float* __restrict__ w2, const float* __restrict__ w3,
    const float* __restrict__ w4, unsigned short* __restrict__ out)
{
  const float* srcs[5] = {w0, w1, w2, w3, w4};
  const float* s = srcs[blockIdx.x];
  unsigned short* o = out + (size_t)blockIdx.x * 16384;
  for (int i = threadIdx.x; i < 16384; i += 256) {
    int c = i >> 7, k = i & 127;
    o[i] = f2bf(s[(size_t)k * 128 + c]);   // Wt[c][k] = W[k][c]
  }
}

// ---- MFMA GEMM, weights staged in LDS (32KB, swizzled), A prefetched ----
template<bool ACT, bool HAS2, bool A1F32>
__global__ __launch_bounds__(256) void k_mgemm(
    const void* __restrict__ A1v, const unsigned short* __restrict__ Wt1,
    const float* __restrict__ bias,
    const unsigned short* __restrict__ A2b, const unsigned short* __restrict__ Wt2,
    unsigned short* __restrict__ Cb, int nrows)
{
  __shared__ char wlds[32768];    // one 128x128 bf16 weight matrix, XOR-swizzled
  const int t    = threadIdx.x;
  const int wave = t >> 6;
  const int lane = t & 63;
  const int lr   = lane & 15;
  const int lg   = lane >> 4;
  const int r0   = blockIdx.x * 64 + wave * 16;
  int arow = r0 + lr; if (arow >= nrows) arow = nrows - 1;

  // prefetch ALL A fragments (8x16B in flight; overlaps weight staging)
  short8 a1[4], a2[4];
  #pragma unroll
  for (int ks = 0; ks < 4; ++ks) {
    const int k0 = ks * 32 + lg * 8;
    if (A1F32) {
      const float* A = (const float*)A1v;
      float4 f0 = *(const float4*)(A + (size_t)arow * 128 + k0);
      float4 f1 = *(const float4*)(A + (size_t)arow * 128 + k0 + 4);
      a1[ks][0] = (short)f2bf(f0.x); a1[ks][1] = (short)f2bf(f0.y);
      a1[ks][2] = (short)f2bf(f0.z); a1[ks][3] = (short)f2bf(f0.w);
      a1[ks][4] = (short)f2bf(f1.x); a1[ks][5] = (short)f2bf(f1.y);
      a1[ks][6] = (short)f2bf(f1.z); a1[ks][7] = (short)f2bf(f1.w);
    } else {
      a1[ks] = *(const short8*)((const unsigned short*)A1v + (size_t)arow * 128 + k0);
    }
  }
  if (HAS2) {
    #pragma unroll
    for (int ks = 0; ks < 4; ++ks) {
      const int k0 = ks * 32 + lg * 8;
      a2[ks] = *(const short8*)(A2b + (size_t)arow * 128 + k0);
    }
  }

  f32x4 acc[8];
  #pragma unroll
  for (int i = 0; i < 8; ++i) acc[i] = (f32x4){0.f, 0.f, 0.f, 0.f};

  // ---- pass 1: stage Wt1 into LDS (coalesced 16B, swizzled store) ----
  #pragma unroll
  for (int i = 0; i < 8; ++i) {
    int o = (i * 256 + t) * 16;                 // linear byte 0..32752
    uint4 v = *(const uint4*)((const char*)Wt1 + o);
    int row = o >> 8, w = o & 255;
    *(uint4*)(wlds + row * 256 + (w ^ ((row & 7) << 4))) = v;
  }
  __syncthreads();
  #pragma unroll
  for (int ks = 0; ks < 4; ++ks) {
    #pragma unroll
    for (int cb = 0; cb < 8; ++cb) {
      int r = cb * 16 + lr;
      int wb = ks * 64 + lg * 16;
      short8 bv = *(const short8*)(wlds + r * 256 + (wb ^ ((r & 7) << 4)));
      acc[cb] = __builtin_amdgcn_mfma_f32_16x16x32_bf16(a1[ks], bv, acc[cb], 0, 0, 0);
    }
  }

  if (HAS2) {
    __syncthreads();   // WAR before restage
    #pragma unroll
    for (int i = 0; i < 8; ++i) {
      int o = (i * 256 + t) * 16;
      uint4 v = *(const uint4*)((const char*)Wt2 + o);
      int row = o >> 8, w = o & 255;
      *(uint4*)(wlds + row * 256 + (w ^ ((row & 7) << 4))) = v;
    }
    __syncthreads();
    #pragma unroll
    for (int ks = 0; ks < 4; ++ks) {
      #pragma unroll
      for (int cb = 0; cb < 8; ++cb) {
        int r = cb * 16 + lr;
        int wb = ks * 64 + lg * 16;
        short8 bv = *(const short8*)(wlds + r * 256 + (wb ^ ((r & 7) << 4)));
        acc[cb] = __builtin_amdgcn_mfma_f32_16x16x32_bf16(a2[ks], bv, acc[cb], 0, 0, 0);
      }
    }
  }

  #pragma unroll
  for (int cb = 0; cb < 8; ++cb) {
    const int col = cb * 16 + lr;
    const float bcol = bias[col];
    #pragma unroll
    for (int reg = 0; reg < 4; ++reg) {
      int r = r0 + lg * 4 + reg;
      if (r < nrows) {
        float o = acc[cb][reg] + bcol;
        if (ACT) o = o > 0.f ? o : o * NEG_SLOPE;
        Cb[(size_t)r * 128 + col] = f2bf(o);
      }
    }
  }
}

// --- bucketize: counting sort of edges by dst>>8 (transposed hist/offs layout) ---

__global__ __launch_bounds__(256) void k_hist(const int* __restrict__ dst,
    int* __restrict__ hist, int E, int NB)
{
  __shared__ int lh[256];
  int t = threadIdx.x;
  lh[t] = 0;
  __syncthreads();
  int chunk = (E + NBE - 1) / NBE;
  int s = blockIdx.x * chunk;
  int e = min(E, s + chunk);
  for (int i = s + t; i < e; i += 256)
    atomicAdd(&lh[dst[i] >> 8], 1);
  __syncthreads();
  hist[blockIdx.x * 256 + t] = lh[t];
  (void)NB;
}

__global__ __launch_bounds__(256) void k_scan(const int* __restrict__ hist,
    int* __restrict__ offs, int NB)
{
  __shared__ int tot[256];
  int t = threadIdx.x;
  int run = 0;
  #pragma unroll 8
  for (int b = 0; b < NBE; ++b) run += hist[b * 256 + t];
  tot[t] = run;
  __syncthreads();
  int val = run;
  for (int o = 1; o < 256; o <<= 1) {
    int x = (t >= o) ? tot[t - o] : 0;
    __syncthreads();
    val += x; tot[t] = val;
    __syncthreads();
  }
  int acc = val - run;
  #pragma unroll 8
  for (int b = 0; b < NBE; ++b) {
    offs[b * 256 + t] = acc;
    acc += hist[b * 256 + t];
  }
  (void)NB;
}

// rec = (dst&255)<<16 | src  (src < 65536)
__global__ __launch_bounds__(256) void k_scatter(const int* __restrict__ src,
    const int* __restrict__ dst, const int* __restrict__ offs,
    unsigned int* __restrict__ recs, int E, int NB)
{
  __shared__ int lcnt[256];
  __shared__ int loff[256];
  int t = threadIdx.x;
  lcnt[t] = 0;
  loff[t] = offs[blockIdx.x * 256 + t];
  __syncthreads();
  int chunk = (E + NBE - 1) / NBE;
  int s = blockIdx.x * chunk;
  int e = min(E, s + chunk);
  for (int i = s + t; i < e; i += 256) {
    int d = dst[i];
    int b = d >> 8;
    int r = atomicAdd(&lcnt[b], 1);
    recs[loff[b] + r] = ((unsigned int)(d & 255) << 16) | (unsigned int)src[i];
  }
  (void)NB;
}

// --- within-bucket counting sort -> per-node CSR (int LDS atomics only) ---
__global__ __launch_bounds__(256) void k_csr(const unsigned int* __restrict__ recs,
    const int* __restrict__ offs, int* __restrict__ adj,
    int* __restrict__ offs2, int* __restrict__ cnt, int N, int NB, int E)
{
  __shared__ int lcnt[256];
  __shared__ int lpos[256];
  const int t  = threadIdx.x;
  const int b  = blockIdx.x;
  const int bs = offs[b];
  const int be = (b + 1 < NB) ? offs[b + 1] : E;
  lcnt[t] = 0;
  __syncthreads();
  for (int i = bs + t; i < be; i += 256)
    atomicAdd(&lcnt[recs[i] >> 16], 1);
  __syncthreads();
  int v = lcnt[t];
  lpos[t] = v;
  __syncthreads();
  int val = v;
  for (int o = 1; o < 256; o <<= 1) {
    int x = (t >= o) ? lpos[t - o] : 0;
    __syncthreads();
    val += x; lpos[t] = val;
    __syncthreads();
  }
  int excl = val - v;
  int node = b * BNODES + t;
  if (node < N) { cnt[node] = v; offs2[node] = bs + excl; }
  lcnt[t] = excl;
  __syncthreads();
  for (int i = bs + t; i < be; i += 256) {
    unsigned int r = recs[i];
    int ld = r >> 16;
    int p = atomicAdd(&lcnt[ld], 1);
    adj[bs + p] = (int)(r & 0xffffu);
  }
}

// Mean aggregation over fp8 rows, XCD-aligned block mapping.
__global__ __launch_bounds__(256) void k_agg(const unsigned int* __restrict__ x8,
    const int* __restrict__ adj, const int* __restrict__ offs2,
    const int* __restrict__ cnt, unsigned int* __restrict__ aggb, int n, int nJ)
{
  const int Q   = (nJ + 7) >> 3;
  const int x   = blockIdx.x & 7;
  const int t2  = blockIdx.x >> 3;
  const int jj  = t2 % Q;
  const int sub = t2 / Q;              // 0..15
  const int j   = x + (jj << 3);
  if (j >= nJ) return;
  int node = j * 64 + sub * 4 + (threadIdx.x >> 6);
  if (node >= n) return;

  const int lane = threadIdx.x & 63;
  const int l = lane & 15;
  const int q = lane >> 4;
  const int c = cnt[node];
  const int* __restrict__ a = adj + offs2[node];

  f32x2 acc[4];
  #pragma unroll
  for (int jv = 0; jv < 4; ++jv) acc[jv] = (f32x2){0.f, 0.f};

  if (c > 0) {
    const int cm1 = c - 1;
    for (int e0 = 0; e0 < c; e0 += 32) {
      int idx[8];
      #pragma unroll
      for (int s = 0; s < 8; ++s)
        idx[s] = a[min(e0 + s * 4 + q, cm1)];
      uint2 v[8];
      #pragma unroll
      for (int s = 0; s < 8; ++s)
        v[s] = *(const uint2*)(x8 + (size_t)idx[s] * 32 + l * 2);
      #pragma unroll
      for (int s = 0; s < 8; ++s) {
        float m = (e0 + s * 4 + q < c) ? 1.f : 0.f;
        f32x2 mm = (f32x2){m, m};
        acc[0] += mm * fp8pair<false>(v[s].x);
        acc[1] += mm * fp8pair<true >(v[s].x);
        acc[2] += mm * fp8pair<false>(v[s].y);
        acc[3] += mm * fp8pair<true >(v[s].y);
      }
    }
    #pragma unroll
    for (int jv = 0; jv < 4; ++jv) {
      float a0 = acc[jv][0], a1 = acc[jv][1];
      a0 += __shfl_xor(a0, 16, 64);
      a0 += __shfl_xor(a0, 32, 64);
      a1 += __shfl_xor(a1, 16, 64);
      a1 += __shfl_xor(a1, 32, 64);
      acc[jv][0] = a0; acc[jv][1] = a1;
    }
  }

  if (q == 0) {
    float sc = (c > 0) ? 1.f / (float)c : 0.f;
    uint4 w;
    w.x = (unsigned)f2bf(acc[0][0] * sc) | ((unsigned)f2bf(acc[0][1] * sc) << 16);
    w.y = (unsigned)f2bf(acc[1][0] * sc) | ((unsigned)f2bf(acc[1][1] * sc) << 16);
    w.z = (unsigned)f2bf(acc[2][0] * sc) | ((unsigned)f2bf(acc[2][1] * sc) << 16);
    w.w = (unsigned)f2bf(acc[3][0] * sc) | ((unsigned)f2bf(acc[3][1] * sc) << 16);
    *(uint4*)(aggb + (size_t)node * 64 + l * 4) = w;
  }
}

// out[r][0..2] = x2[r] @ W_out + b_out; block j handles rows 64j..
__global__ __launch_bounds__(256) void k_out(const unsigned int* __restrict__ x2w,
    const float* __restrict__ Wo, const float* __restrict__ bo,
    float* __restrict__ out, int n)
{
  int wave = threadIdx.x >> 6;
  int lane = threadIdx.x & 63;
  float w0a = Wo[(2*lane)*3 + 0], w0b = Wo[(2*lane)*3 + 1], w0c = Wo[(2*lane)*3 + 2];
  float w1a = Wo[(2*lane+1)*3 + 0], w1b = Wo[(2*lane+1)*3 + 1], w1c = Wo[(2*lane+1)*3 + 2];
  float b0 = bo[0], b1 = bo[1], b2 = bo[2];
  int rbase = blockIdx.x * 64 + wave * 16;
  for (int i = 0; i < 16; ++i) {
    int r = rbase + i;
    if (r >= n) break;
    unsigned int v = x2w[(size_t)r * 64 + lane];
    float xl = __uint_as_float(v << 16);
    float xh = __uint_as_float(v & 0xffff0000u);
    float o0 = xl * w0a + xh * w1a;
    float o1 = xl * w0b + xh * w1b;
    float o2 = xl * w0c + xh * w1c;
    for (int off = 32; off; off >>= 1) {
      o0 += __shfl_xor(o0, off, 64);
      o1 += __shfl_xor(o1, off, 64);
      o2 += __shfl_xor(o2, off, 64);
    }
    if (lane == 0) {
      out[(size_t)r * 3 + 0] = o0 + b0;
      out[(size_t)r * 3 + 1] = o1 + b1;
      out[(size_t)r * 3 + 2] = o2 + b2;
    }
  }
}

extern "C" void kernel_launch(void* const* d_in, const int* in_sizes, int n_in,
                              void* d_out, int out_size, void* d_ws, size_t ws_size,
                              hipStream_t stream)
{
  const float* feature = (const float*)d_in[0];
  const int*   ei      = (const int*)d_in[1];
  // d_in[2] edge_type: unused by the reference
  const float* W_in = (const float*)d_in[3];
  const float* b_in = (const float*)d_in[4];
  const float* W1l  = (const float*)d_in[5];
  const float* b1l  = (const float*)d_in[6];
  const float* W1r  = (const float*)d_in[7];
  const float* W2l  = (const float*)d_in[8];
  const float* b2l  = (const float*)d_in[9];
  const float* W2r  = (const float*)d_in[10];
  const float* Wo   = (const float*)d_in[11];
  const float* bo   = (const float*)d_in[12];
  float* out = (float*)d_out;

  const int N = in_sizes[0] / 128;
  const int E = in_sizes[1] / 2;
  const int NB = (N + BNODES - 1) / BNODES;
  const int* src = ei;
  const int* dst = ei + E;

  char* ws = (char*)d_ws;
  size_t off = 0;
  auto alloc = [&](size_t bytes) {
    char* p = ws + off;
    off = (off + bytes + 255) & ~(size_t)255;
    return p;
  };
  unsigned int* xb    = (unsigned int*)alloc((size_t)N * 64 * 4); // bf16 x0
  unsigned int* yb    = (unsigned int*)alloc((size_t)N * 64 * 4); // bf16 x1
  unsigned int* zb    = (unsigned int*)alloc((size_t)N * 64 * 4); // bf16 x2
  unsigned int* agb   = (unsigned int*)alloc((size_t)N * 64 * 4); // bf16 agg
  unsigned int* x8    = (unsigned int*)alloc((size_t)N * 32 * 4); // fp8 x0
  unsigned int* y8    = (unsigned int*)alloc((size_t)N * 32 * 4); // fp8 x1
  unsigned int* recs  = (unsigned int*)alloc((size_t)E * 4);
  int*          adj   = (int*)alloc((size_t)E * 4);
  int*          hist  = (int*)alloc((size_t)256 * NBE * 4);
  int*          offs  = (int*)alloc((size_t)256 * NBE * 4);
  int*          offs2 = (int*)alloc((size_t)N * 4);
  int*          cnt   = (int*)alloc((size_t)N * 4);
  unsigned short* wtb = (unsigned short*)alloc((size_t)5 * 16384 * 2);
  (void)ws_size; (void)n_in; (void)out_size;

  unsigned short* WtIn = wtb;
  unsigned short* Wt1l = wtb + 16384;
  unsigned short* Wt1r = wtb + 2 * 16384;
  unsigned short* Wt2l = wtb + 3 * 16384;
  unsigned short* Wt2r = wtb + 4 * 16384;

  unsigned short* xbs  = (unsigned short*)xb;
  unsigned short* ybs  = (unsigned short*)yb;
  unsigned short* zbs  = (unsigned short*)zb;
  unsigned short* agbs = (unsigned short*)agb;

  dim3 blk(256);
  int gGemm = (N + 63) / 64;
  int Q     = (gGemm + 7) / 8;
  int gAgg  = 8 * Q * 16;          // XCD-aligned agg grid
  int gCvt  = (N * 32 + 255) / 256;

  // weight prep + edge bucketing (independent)
  k_prep_w<<<5, blk, 0, stream>>>(W_in, W1l, W1r, W2l, W2r, wtb);
  k_hist<<<NBE, blk, 0, stream>>>(dst, hist, E, NB);
  k_scan<<<1, blk, 0, stream>>>(hist, offs, NB);
  k_scatter<<<NBE, blk, 0, stream>>>(src, dst, offs, recs, E, NB);
  k_csr<<<NB, blk, 0, stream>>>(recs, offs, adj, offs2, cnt, N, NB, E);

  // x0 = leaky_relu(feature @ W_in + b_in)  -> bf16 xb, fp8 x8
  k_mgemm<true,  false, true ><<<gGemm, blk, 0, stream>>>(
      feature, WtIn, b_in, nullptr, nullptr, xbs, N);
  k_tofp8<<<gCvt, blk, 0, stream>>>(xb, x8, N * 32);

  // layer 1
  k_agg<<<gAgg, blk, 0, stream>>>(x8, adj, offs2, cnt, agb, N, gGemm);
  k_mgemm<false, true,  false><<<gGemm, blk, 0, stream>>>(
      agbs, Wt1l, b1l, xbs, Wt1r, ybs, N);
  k_tofp8<<<gCvt, blk, 0, stream>>>(yb, y8, N * 32);

  // layer 2
  k_agg<<<gAgg, blk, 0, stream>>>(y8, adj, offs2, cnt, agb, N, gGemm);
  k_mgemm<false, true,  false><<<gGemm, blk, 0, stream>>>(
      agbs, Wt2l, b2l, ybs, Wt2r, zbs, N);

  // output projection (block-aligned rows)
  k_out<<<gGemm, blk, 0, stream>>>(zb, Wo, bo, out, N);
}

// Round 13
// 172.087 us; speedup vs baseline: 1.7794x; 1.2222x over previous
//
#include <hip/hip_runtime.h>
#include <hip/hip_bf16.h>

#define NEG_SLOPE 0.01f
#define BNODES 256      // nodes per bucket (dst>>8)
#define NBE 256         // blocks for hist/scatter edge passes

typedef __attribute__((ext_vector_type(8))) short short8;
typedef __attribute__((ext_vector_type(4))) float f32x4;
typedef __attribute__((ext_vector_type(2))) float f32x2;

__device__ __forceinline__ unsigned short f2bf(float f) {
  unsigned int u = __float_as_uint(f);
  u = (u + 0x7fffu + ((u >> 16) & 1u)) >> 16;
  return (unsigned short)u;
}
__device__ __forceinline__ float bf2f(unsigned short b) {
  return __uint_as_float(((unsigned)b) << 16);
}

// ---------- fp8 pack/unpack (HW cvt if available; consistent manual fallback) ----------
#if defined(__has_builtin)
#if __has_builtin(__builtin_amdgcn_cvt_pk_f32_fp8) && __has_builtin(__builtin_amdgcn_cvt_pk_fp8_f32)
#define HAS_FP8_CVT 1
#endif
#endif
#ifndef HAS_FP8_CVT
#define HAS_FP8_CVT 0
#endif

__device__ __forceinline__ float dec1(unsigned b) {
  unsigned s = (b & 0x80u) << 24;
  unsigned em = b & 0x7fu;
  float v = (em < 8) ? (float)em * 0.001953125f
          : __uint_as_float((((em >> 3) + 120u) << 23) | ((em & 7u) << 20));
  return __uint_as_float(s ^ __float_as_uint(v));
}

__device__ __forceinline__ unsigned enc1(float f) {
  unsigned u = __float_as_uint(f);
  unsigned s = (u >> 24) & 0x80u;
  float a = fabsf(f);
  a = fminf(a, 480.f);
  unsigned code;
  if (a < 0.015625f) {
    code = (unsigned)__float2int_rn(a * 512.f);
  } else {
    unsigned ua = __float_as_uint(a);
    unsigned r = ua + 0x7ffffu + ((ua >> 20) & 1u);
    code = (((r >> 23) - 120u) << 3) | ((r >> 20) & 7u);
    if (code > 0x7fu) code = 0x7fu;
  }
  return s | code;
}

template<bool HI>
__device__ __forceinline__ f32x2 fp8pair(unsigned int w) {
#if HAS_FP8_CVT
  return __builtin_amdgcn_cvt_pk_f32_fp8((int)w, HI);
#else
  unsigned sh = HI ? 16u : 0u;
  f32x2 r;
  r[0] = dec1((w >> sh) & 0xffu);
  r[1] = dec1((w >> (sh + 8)) & 0xffu);
  return r;
#endif
}

template<bool HI>
__device__ __forceinline__ unsigned fp8pack(float a, float b, unsigned old) {
#if HAS_FP8_CVT
  return (unsigned)__builtin_amdgcn_cvt_pk_fp8_f32(a, b, (int)old, HI);
#else
  unsigned code = enc1(a) | (enc1(b) << 8);
  return HI ? ((old & 0x0000ffffu) | (code << 16)) : ((old & 0xffff0000u) | code);
#endif
}

// ---- prep+hist merged: blocks 0..4 = weight transpose, 5.. = edge histogram ----
__global__ __launch_bounds__(256) void k_prep_hist(
    const float* __restrict__ w0, const float* __restrict__ w1,
    const float* __restrict__ w2, const float* __restrict__ w3,
    const float* __restrict__ w4, unsigned short* __restrict__ wout,
    const int* __restrict__ dst, int* __restrict__ hist, int E)
{
  if (blockIdx.x < 5) {
    const float* srcs[5] = {w0, w1, w2, w3, w4};
    const float* s = srcs[blockIdx.x];
    unsigned short* o = wout + (size_t)blockIdx.x * 16384;
    for (int i = threadIdx.x; i < 16384; i += 256) {
      int c = i >> 7, k = i & 127;
      o[i] = f2bf(s[(size_t)k * 128 + c]);   // Wt[c][k] = W[k][c]
    }
    return;
  }
  __shared__ int lh[256];
  const int bb = blockIdx.x - 5;
  int t = threadIdx.x;
  lh[t] = 0;
  __syncthreads();
  int chunk = (E + NBE - 1) / NBE;
  int s = bb * chunk;
  int e = min(E, s + chunk);
  for (int i = s + t; i < e; i += 256)
    atomicAdd(&lh[dst[i] >> 8], 1);
  __syncthreads();
  hist[bb * 256 + t] = lh[t];
}

__global__ __launch_bounds__(256) void k_scan(const int* __restrict__ hist,
    int* __restrict__ offs, int NB)
{
  __shared__ int tot[256];
  int t = threadIdx.x;
  int run = 0;
  #pragma unroll 8
  for (int b = 0; b < NBE; ++b) run += hist[b * 256 + t];
  tot[t] = run;
  __syncthreads();
  int val = run;
  for (int o = 1; o < 256; o <<= 1) {
    int x = (t >= o) ? tot[t - o] : 0;
    __syncthreads();
    val += x; tot[t] = val;
    __syncthreads();
  }
  int acc = val - run;
  #pragma unroll 8
  for (int b = 0; b < NBE; ++b) {
    offs[b * 256 + t] = acc;
    acc += hist[b * 256 + t];
  }
  (void)NB;
}

// rec = (dst&255)<<16 | src  (src < 65536)
__global__ __launch_bounds__(256) void k_scatter(const int* __restrict__ src,
    const int* __restrict__ dst, const int* __restrict__ offs,
    unsigned int* __restrict__ recs, int E)
{
  __shared__ int lcnt[256];
  __shared__ int loff[256];
  int t = threadIdx.x;
  lcnt[t] = 0;
  loff[t] = offs[blockIdx.x * 256 + t];
  __syncthreads();
  int chunk = (E + NBE - 1) / NBE;
  int s = blockIdx.x * chunk;
  int e = min(E, s + chunk);
  for (int i = s + t; i < e; i += 256) {
    int d = dst[i];
    int b = d >> 8;
    int r = atomicAdd(&lcnt[b], 1);
    recs[loff[b] + r] = ((unsigned int)(d & 255) << 16) | (unsigned int)src[i];
  }
}

// --- csr body (within-bucket counting sort -> per-node CSR) ---
__device__ __forceinline__ void csr_body(int b, int* lcnt, int* lpos,
    const unsigned int* __restrict__ recs, const int* __restrict__ offs,
    int* __restrict__ adj, int* __restrict__ offs2, int* __restrict__ cnt,
    int N, int NB, int E)
{
  const int t  = threadIdx.x;
  const int bs = offs[b];
  const int be = (b + 1 < NB) ? offs[b + 1] : E;
  lcnt[t] = 0;
  __syncthreads();
  for (int i = bs + t; i < be; i += 256)
    atomicAdd(&lcnt[recs[i] >> 16], 1);
  __syncthreads();
  int v = lcnt[t];
  lpos[t] = v;
  __syncthreads();
  int val = v;
  for (int o = 1; o < 256; o <<= 1) {
    int x = (t >= o) ? lpos[t - o] : 0;
    __syncthreads();
    val += x; lpos[t] = val;
    __syncthreads();
  }
  int excl = val - v;
  int node = b * BNODES + t;
  if (node < N) { cnt[node] = v; offs2[node] = bs + excl; }
  lcnt[t] = excl;
  __syncthreads();
  for (int i = bs + t; i < be; i += 256) {
    unsigned int r = recs[i];
    int ld = r >> 16;
    int p = atomicAdd(&lcnt[ld], 1);
    adj[bs + p] = (int)(r & 0xffffu);
  }
}

// ---- GEMM body: LDS-staged weights, A prefetch, LDS-staged C epilogue.
// Emits: bf16 C (!OUTPROJ), fp8 mirror (EMIT8), or 3-col projection (OUTPROJ).
template<bool ACT, bool HAS2, bool A1F32, bool EMIT8, bool OUTPROJ>
__device__ __forceinline__ void mgemm_body(int b, char* wlds,
    const void* __restrict__ A1v, const unsigned short* __restrict__ Wt1,
    const float* __restrict__ bias,
    const unsigned short* __restrict__ A2b, const unsigned short* __restrict__ Wt2,
    unsigned short* __restrict__ Cb, unsigned int* __restrict__ C8,
    const float* __restrict__ Wo, const float* __restrict__ bo,
    float* __restrict__ outp, int nrows)
{
  const int t    = threadIdx.x;
  const int wave = t >> 6;
  const int lane = t & 63;
  const int lr   = lane & 15;
  const int lg   = lane >> 4;
  const int r0   = b * 64 + wave * 16;
  int arow = r0 + lr; if (arow >= nrows) arow = nrows - 1;

  // prefetch ALL A fragments (overlaps weight staging)
  short8 a1[4], a2[4];
  #pragma unroll
  for (int ks = 0; ks < 4; ++ks) {
    const int k0 = ks * 32 + lg * 8;
    if (A1F32) {
      const float* A = (const float*)A1v;
      float4 f0 = *(const float4*)(A + (size_t)arow * 128 + k0);
      float4 f1 = *(const float4*)(A + (size_t)arow * 128 + k0 + 4);
      a1[ks][0] = (short)f2bf(f0.x); a1[ks][1] = (short)f2bf(f0.y);
      a1[ks][2] = (short)f2bf(f0.z); a1[ks][3] = (short)f2bf(f0.w);
      a1[ks][4] = (short)f2bf(f1.x); a1[ks][5] = (short)f2bf(f1.y);
      a1[ks][6] = (short)f2bf(f1.z); a1[ks][7] = (short)f2bf(f1.w);
    } else {
      a1[ks] = *(const short8*)((const unsigned short*)A1v + (size_t)arow * 128 + k0);
    }
  }
  if (HAS2) {
    #pragma unroll
    for (int ks = 0; ks < 4; ++ks) {
      const int k0 = ks * 32 + lg * 8;
      a2[ks] = *(const short8*)(A2b + (size_t)arow * 128 + k0);
    }
  }

  f32x4 acc[8];
  #pragma unroll
  for (int i = 0; i < 8; ++i) acc[i] = (f32x4){0.f, 0.f, 0.f, 0.f};

  // pass 1: stage Wt1 into LDS (coalesced 16B, swizzled store)
  #pragma unroll
  for (int i = 0; i < 8; ++i) {
    int o = (i * 256 + t) * 16;
    uint4 v = *(const uint4*)((const char*)Wt1 + o);
    int row = o >> 8, w = o & 255;
    *(uint4*)(wlds + row * 256 + (w ^ ((row & 7) << 4))) = v;
  }
  __syncthreads();
  #pragma unroll
  for (int ks = 0; ks < 4; ++ks) {
    #pragma unroll
    for (int cb = 0; cb < 8; ++cb) {
      int r = cb * 16 + lr;
      int wb = ks * 64 + lg * 16;
      short8 bv = *(const short8*)(wlds + r * 256 + (wb ^ ((r & 7) << 4)));
      acc[cb] = __builtin_amdgcn_mfma_f32_16x16x32_bf16(a1[ks], bv, acc[cb], 0, 0, 0);
    }
  }

  if (HAS2) {
    __syncthreads();   // WAR before restage
    #pragma unroll
    for (int i = 0; i < 8; ++i) {
      int o = (i * 256 + t) * 16;
      uint4 v = *(const uint4*)((const char*)Wt2 + o);
      int row = o >> 8, w = o & 255;
      *(uint4*)(wlds + row * 256 + (w ^ ((row & 7) << 4))) = v;
    }
    __syncthreads();
    #pragma unroll
    for (int ks = 0; ks < 4; ++ks) {
      #pragma unroll
      for (int cb = 0; cb < 8; ++cb) {
        int r = cb * 16 + lr;
        int wb = ks * 64 + lg * 16;
        short8 bv = *(const short8*)(wlds + r * 256 + (wb ^ ((r & 7) << 4)));
        acc[cb] = __builtin_amdgcn_mfma_f32_16x16x32_bf16(a2[ks], bv, acc[cb], 0, 0, 0);
      }
    }
  }

  // ---- epilogue: stage C (bf16) into LDS (reuse weight buffer), then emit ----
  __syncthreads();   // all weight reads done
  #pragma unroll
  for (int cb = 0; cb < 8; ++cb) {
    const int col = cb * 16 + lr;
    const float bcol = bias[col];
    #pragma unroll
    for (int reg = 0; reg < 4; ++reg) {
      const int lrow = wave * 16 + lg * 4 + reg;   // local row 0..63
      float o = acc[cb][reg] + bcol;
      if (ACT) o = o > 0.f ? o : o * NEG_SLOPE;
      *(unsigned short*)(wlds + lrow * 256 + col * 2) = f2bf(o);
    }
  }
  __syncthreads();

  if (!OUTPROJ) {
    // coalesced bf16 C store
    #pragma unroll
    for (int i = 0; i < 4; ++i) {
      int idx = i * 256 + t;                 // 0..1023
      int row = idx >> 4, w = idx & 15;
      int r = b * 64 + row;
      if (r < nrows)
        *(uint4*)((char*)Cb + (size_t)r * 256 + w * 16) = *(const uint4*)(wlds + row * 256 + w * 16);
    }
    if (EMIT8) {
      // fp8 mirror: 8 cols per task
      #pragma unroll
      for (int i = 0; i < 4; ++i) {
        int idx = i * 256 + t;               // 0..1023
        int row = idx >> 4, seg = idx & 15;  // cols 8seg..8seg+7
        int r = b * 64 + row;
        if (r < nrows) {
          const unsigned short* p = (const unsigned short*)(wlds + row * 256 + seg * 16);
          unsigned w0 = 0, w1 = 0;
          w0 = fp8pack<false>(bf2f(p[0]), bf2f(p[1]), w0);
          w0 = fp8pack<true >(bf2f(p[2]), bf2f(p[3]), w0);
          w1 = fp8pack<false>(bf2f(p[4]), bf2f(p[5]), w1);
          w1 = fp8pack<true >(bf2f(p[6]), bf2f(p[7]), w1);
          *(uint2*)(C8 + (size_t)r * 32 + seg * 2) = make_uint2(w0, w1);
        }
      }
    }
  } else {
    // out-projection: thread t -> row t>>2, quarter q = t&3 covers cols 32q..
    const int row = t >> 2, q = t & 3;
    const int r = b * 64 + row;
    float o0 = 0.f, o1 = 0.f, o2 = 0.f;
    const unsigned short* p = (const unsigned short*)(wlds + row * 256 + q * 64);
    #pragma unroll
    for (int i = 0; i < 32; ++i) {
      float x = bf2f(p[i]);
      const float* wr = Wo + (q * 32 + i) * 3;
      o0 += x * wr[0]; o1 += x * wr[1]; o2 += x * wr[2];
    }
    o0 += __shfl_xor(o0, 1, 64); o0 += __shfl_xor(o0, 2, 64);
    o1 += __shfl_xor(o1, 1, 64); o1 += __shfl_xor(o1, 2, 64);
    o2 += __shfl_xor(o2, 1, 64); o2 += __shfl_xor(o2, 2, 64);
    if (q == 0 && r < nrows) {
      outp[(size_t)r * 3 + 0] = o0 + bo[0];
      outp[(size_t)r * 3 + 1] = o1 + bo[1];
      outp[(size_t)r * 3 + 2] = o2 + bo[2];
    }
  }
}

// ---- merged: blocks 0..NB-1 = CSR build; NB.. = input GEMM (feature->x0) ----
__global__ __launch_bounds__(256) void k_csr_mgemm0(
    const unsigned int* __restrict__ recs, const int* __restrict__ offs,
    int* __restrict__ adj, int* __restrict__ offs2, int* __restrict__ cnt,
    const float* __restrict__ feature, const unsigned short* __restrict__ WtIn,
    const float* __restrict__ b_in,
    unsigned short* __restrict__ xbs, unsigned int* __restrict__ x8,
    int N, int NB, int E)
{
  __shared__ char wlds[32768];
  if ((int)blockIdx.x < NB) {
    int* li = (int*)wlds;
    csr_body(blockIdx.x, li, li + 256, recs, offs, adj, offs2, cnt, N, NB, E);
    return;
  }
  mgemm_body<true, false, true, true, false>(blockIdx.x - NB, wlds,
      feature, WtIn, b_in, nullptr, nullptr, xbs, x8, nullptr, nullptr, nullptr, N);
}

// ---- layer GEMM: dual matmul, emits bf16 (+fp8 if EMIT8) or projection ----
template<bool EMIT8, bool OUTPROJ>
__global__ __launch_bounds__(256) void k_mgemm(
    const unsigned short* __restrict__ A1b, const unsigned short* __restrict__ Wt1,
    const float* __restrict__ bias,
    const unsigned short* __restrict__ A2b, const unsigned short* __restrict__ Wt2,
    unsigned short* __restrict__ Cb, unsigned int* __restrict__ C8,
    const float* __restrict__ Wo, const float* __restrict__ bo,
    float* __restrict__ outp, int nrows)
{
  __shared__ char wlds[32768];
  mgemm_body<false, true, false, EMIT8, OUTPROJ>(blockIdx.x, wlds,
      A1b, Wt1, bias, A2b, Wt2, Cb, C8, Wo, bo, outp, nrows);
}

// Mean aggregation over fp8 rows, XCD-aligned block mapping.
__global__ __launch_bounds__(256) void k_agg(const unsigned int* __restrict__ x8,
    const int* __restrict__ adj, const int* __restrict__ offs2,
    const int* __restrict__ cnt, unsigned int* __restrict__ aggb, int n, int nJ)
{
  const int Q   = (nJ + 7) >> 3;
  const int x   = blockIdx.x & 7;
  const int t2  = blockIdx.x >> 3;
  const int jj  = t2 % Q;
  const int sub = t2 / Q;              // 0..15
  const int j   = x + (jj << 3);
  if (j >= nJ) return;
  int node = j * 64 + sub * 4 + (threadIdx.x >> 6);
  if (node >= n) return;

  const int lane = threadIdx.x & 63;
  const int l = lane & 15;
  const int q = lane >> 4;
  const int c = cnt[node];
  const int* __restrict__ a = adj + offs2[node];

  f32x2 acc[4];
  #pragma unroll
  for (int jv = 0; jv < 4; ++jv) acc[jv] = (f32x2){0.f, 0.f};

  if (c > 0) {
    const int cm1 = c - 1;
    for (int e0 = 0; e0 < c; e0 += 32) {
      int idx[8];
      #pragma unroll
      for (int s = 0; s < 8; ++s)
        idx[s] = a[min(e0 + s * 4 + q, cm1)];
      uint2 v[8];
      #pragma unroll
      for (int s = 0; s < 8; ++s)
        v[s] = *(const uint2*)(x8 + (size_t)idx[s] * 32 + l * 2);
      #pragma unroll
      for (int s = 0; s < 8; ++s) {
        float m = (e0 + s * 4 + q < c) ? 1.f : 0.f;
        f32x2 mm = (f32x2){m, m};
        acc[0] += mm * fp8pair<false>(v[s].x);
        acc[1] += mm * fp8pair<true >(v[s].x);
        acc[2] += mm * fp8pair<false>(v[s].y);
        acc[3] += mm * fp8pair<true >(v[s].y);
      }
    }
    #pragma unroll
    for (int jv = 0; jv < 4; ++jv) {
      float a0 = acc[jv][0], a1 = acc[jv][1];
      a0 += __shfl_xor(a0, 16, 64);
      a0 += __shfl_xor(a0, 32, 64);
      a1 += __shfl_xor(a1, 16, 64);
      a1 += __shfl_xor(a1, 32, 64);
      acc[jv][0] = a0; acc[jv][1] = a1;
    }
  }

  if (q == 0) {
    float sc = (c > 0) ? 1.f / (float)c : 0.f;
    uint4 w;
    w.x = (unsigned)f2bf(acc[0][0] * sc) | ((unsigned)f2bf(acc[0][1] * sc) << 16);
    w.y = (unsigned)f2bf(acc[1][0] * sc) | ((unsigned)f2bf(acc[1][1] * sc) << 16);
    w.z = (unsigned)f2bf(acc[2][0] * sc) | ((unsigned)f2bf(acc[2][1] * sc) << 16);
    w.w = (unsigned)f2bf(acc[3][0] * sc) | ((unsigned)f2bf(acc[3][1] * sc) << 16);
    *(uint4*)(aggb + (size_t)node * 64 + l * 4) = w;
  }
}

extern "C" void kernel_launch(void* const* d_in, const int* in_sizes, int n_in,
                              void* d_out, int out_size, void* d_ws, size_t ws_size,
                              hipStream_t stream)
{
  const float* feature = (const float*)d_in[0];
  const int*   ei      = (const int*)d_in[1];
  // d_in[2] edge_type: unused by the reference
  const float* W_in = (const float*)d_in[3];
  const float* b_in = (const float*)d_in[4];
  const float* W1l  = (const float*)d_in[5];
  const float* b1l  = (const float*)d_in[6];
  const float* W1r  = (const float*)d_in[7];
  const float* W2l  = (const float*)d_in[8];
  const float* b2l  = (const float*)d_in[9];
  const float* W2r  = (const float*)d_in[10];
  const float* Wo   = (const float*)d_in[11];
  const float* bo   = (const float*)d_in[12];
  float* out = (float*)d_out;

  const int N = in_sizes[0] / 128;
  const int E = in_sizes[1] / 2;
  const int NB = (N + BNODES - 1) / BNODES;
  const int* src = ei;
  const int* dst = ei + E;

  char* ws = (char*)d_ws;
  size_t off = 0;
  auto alloc = [&](size_t bytes) {
    char* p = ws + off;
    off = (off + bytes + 255) & ~(size_t)255;
    return p;
  };
  unsigned int* xb    = (unsigned int*)alloc((size_t)N * 64 * 4); // bf16 x0
  unsigned int* yb    = (unsigned int*)alloc((size_t)N * 64 * 4); // bf16 x1
  unsigned int* agb   = (unsigned int*)alloc((size_t)N * 64 * 4); // bf16 agg
  unsigned int* x8    = (unsigned int*)alloc((size_t)N * 32 * 4); // fp8 x0
  unsigned int* y8    = (unsigned int*)alloc((size_t)N * 32 * 4); // fp8 x1
  unsigned int* recs  = (unsigned int*)alloc((size_t)E * 4);
  int*          adj   = (int*)alloc((size_t)E * 4);
  int*          hist  = (int*)alloc((size_t)256 * NBE * 4);
  int*          offs  = (int*)alloc((size_t)256 * NBE * 4);
  int*          offs2 = (int*)alloc((size_t)N * 4);
  int*          cnt   = (int*)alloc((size_t)N * 4);
  unsigned short* wtb = (unsigned short*)alloc((size_t)5 * 16384 * 2);
  (void)ws_size; (void)n_in; (void)out_size;

  unsigned short* WtIn = wtb;
  unsigned short* Wt1l = wtb + 16384;
  unsigned short* Wt1r = wtb + 2 * 16384;
  unsigned short* Wt2l = wtb + 3 * 16384;
  unsigned short* Wt2r = wtb + 4 * 16384;

  unsigned short* xbs  = (unsigned short*)xb;
  unsigned short* ybs  = (unsigned short*)yb;
  unsigned short* agbs = (unsigned short*)agb;

  dim3 blk(256);
  int gGemm = (N + 63) / 64;
  int Q     = (gGemm + 7) / 8;
  int gAgg  = 8 * Q * 16;          // XCD-aligned agg grid

  // 1: weight transpose + edge histogram (independent work, one dispatch)
  k_prep_hist<<<5 + NBE, blk, 0, stream>>>(W_in, W1l, W1r, W2l, W2r, wtb,
                                           dst, hist, E);
  // 2: offsets
  k_scan<<<1, blk, 0, stream>>>(hist, offs, NB);
  // 3: bucket scatter
  k_scatter<<<NBE, blk, 0, stream>>>(src, dst, offs, recs, E);
  // 4: CSR build overlapped with input GEMM (x0 bf16 + fp8)
  k_csr_mgemm0<<<NB + gGemm, blk, 0, stream>>>(recs, offs, adj, offs2, cnt,
      feature, WtIn, b_in, xbs, x8, N, NB, E);
  // 5-6: layer 1
  k_agg<<<gAgg, blk, 0, stream>>>(x8, adj, offs2, cnt, agb, N, gGemm);
  k_mgemm<true, false><<<gGemm, blk, 0, stream>>>(
      agbs, Wt1l, b1l, xbs, Wt1r, ybs, y8, nullptr, nullptr, nullptr, N);
  // 7-8: layer 2 + fused output projection
  k_agg<<<gAgg, blk, 0, stream>>>(y8, adj, offs2, cnt, agb, N, gGemm);
  k_mgemm<false, true><<<gGemm, blk, 0, stream>>>(
      agbs, Wt2l, b2l, ybs, Wt2r, nullptr, nullptr, Wo, bo, out, N);
}